// Round 7
// baseline (97.230 us; speedup 1.0000x reference)
//
#include <hip/hip_runtime.h>
#include <math.h>

namespace {

constexpr int N   = 8192;
constexpr int NT  = 256;          // threads per block
constexpr int TR  = 4;            // rows per block (diag reuse)
constexpr int PF4 = N / 4 / NT;   // 8 float4 col-groups per thread per row
constexpr int NW  = NT / 64;      // 4 waves
constexpr float EPS = 1e-6f;
constexpr float NLOG_EPS = 13.815511f;   // -ln(1e-6)
constexpr float NEG_INF  = -3.4e38f;

__device__ __forceinline__ float waveMax(float v) {
#pragma unroll
  for (int off = 32; off; off >>= 1) v = fmaxf(v, __shfl_xor(v, off, 64));
  return v;
}
__device__ __forceinline__ float waveSum(float v) {
#pragma unroll
  for (int off = 32; off; off >>= 1) v += __shfl_xor(v, off, 64);
  return v;
}
__device__ __forceinline__ unsigned waveSumU(unsigned v) {
#pragma unroll
  for (int off = 32; off; off >>= 1) v += (unsigned)__shfl_xor((int)v, off, 64);
  return v;
}

__global__ void diag_extract(const float* __restrict__ sim, float* __restrict__ dg) {
  int i = blockIdx.x * blockDim.x + threadIdx.x;
  if (i < N) dg[i] = sim[(size_t)i * N + i];
}

__launch_bounds__(NT)
__global__ void row_loss(const float* __restrict__ sim,
                         const float* __restrict__ dg,
                         float* __restrict__ pos_out,
                         float* __restrict__ neg_out,
                         unsigned* __restrict__ cnt_out) {
  __shared__ float shm[TR][NW];    // per-wave max, per row
  __shared__ float shz[TR][NW];    // per-wave Z partial, per row
  __shared__ float shn[TR][NW];    // per-wave neg sums, per row
  __shared__ unsigned shc[TR][NW]; // per-wave counts, per row

  const int row0 = blockIdx.x * TR;
  const int t    = threadIdx.x;
  const int wid  = t >> 6;
  const int lane = t & 63;

  const float4* dp = reinterpret_cast<const float4*>(dg);

  float dr[TR];
#pragma unroll
  for (int r = 0; r < TR; ++r) dr[r] = dg[row0 + r];   // uniform scalar loads

  // ---- per-row streaming state ----
  float t1[TR], t2[TR], s1[TR], s2[TR];
  unsigned lc[TR];
#pragma unroll
  for (int r = 0; r < TR; ++r) {
    t1[r] = NEG_INF; t2[r] = NEG_INF;
    s1[r] = NEG_INF; s2[r] = NEG_INF;
    lc[r] = 0;
  }

  // ---- single sweep: one diag load serves TR matrix loads ----
#pragma unroll
  for (int k = 0; k < PF4; ++k) {
    const int idx = k * NT + t;
    float4 dv = dp[idx];
#pragma unroll
    for (int r = 0; r < TR; ++r) {
      const float4* rp = reinterpret_cast<const float4*>(sim + (size_t)(row0 + r) * N);
      float4 v = rp[idx];
#pragma unroll
      for (int c = 0; c < 4; ++c) {
        const float xi = (c == 0) ? v.x  : (c == 1) ? v.y  : (c == 2) ? v.z  : v.w;
        const float dc = (c == 0) ? dv.x : (c == 1) ? dv.y : (c == 2) ? dv.z : dv.w;
        const bool sel = xi > fminf(dr[r], dc);   // diagonal auto-excluded
        lc[r] += sel ? 1u : 0u;
        t2[r] = fmaxf(t2[r], fminf(xi, t1[r]));
        t1[r] = fmaxf(t1[r], xi);
        const float xs = sel ? xi : NEG_INF;
        s2[r] = fmaxf(s2[r], fminf(xs, s1[r]));
        s1[r] = fmaxf(s1[r], xs);
      }
    }
  }

  // ---- block max per row ----
#pragma unroll
  for (int r = 0; r < TR; ++r) {
    float lm = waveMax(t1[r]);
    if (lane == 0) shm[r][wid] = lm;
  }
  __syncthreads();

  float M[TR];
#pragma unroll
  for (int r = 0; r < TR; ++r) {
    float m = shm[r][0];
#pragma unroll
    for (int w = 1; w < NW; ++w) m = fmaxf(m, shm[r][w]);
    M[r] = m;
  }

  // ---- Z per row from kept top-2 (cutoff M-0.2: rel err < 2e-5) ----
#pragma unroll
  for (int r = 0; r < TR; ++r) {
    const float zc = M[r] - 0.2f;
    float zp = 0.0f;
    if (t1[r] > zc) zp += __expf(100.0f * (t1[r] - M[r]));
    if (t2[r] > zc) zp += __expf(100.0f * (t2[r] - M[r]));
    zp = waveSum(zp);
    if (lane == 0) shz[r][wid] = zp;
  }
  __syncthreads();

  float C[TR], xthr[TR];
#pragma unroll
  for (int r = 0; r < TR; ++r) {
    float Z = shz[r][0];
#pragma unroll
    for (int w = 1; w < NW; ++w) Z += shz[r][w];
    C[r]    = fmaf(100.0f, M[r], __logf(Z));       // p = exp(100x - C)
    xthr[r] = (C[r] - NLOG_EPS) * 0.01f;           // below: term == EPS exactly
  }

  // ---- rare exact neg path + baseline EPS, per row ----
#pragma unroll
  for (int r = 0; r < TR; ++r) {
    float negs = 0.0f;
    if (s1[r] > xthr[r]) {
      float p  = __expf(fmaf(100.0f, s1[r], -C[r]));
      float pc = fminf(fmaxf(p, EPS), 1.0f - EPS);
      negs += -__logf(1.0f - pc) - EPS;
    }
    if (s2[r] > xthr[r]) {
      float p  = __expf(fmaf(100.0f, s2[r], -C[r]));
      float pc = fminf(fmaxf(p, EPS), 1.0f - EPS);
      negs += -__logf(1.0f - pc) - EPS;
    }
    negs += EPS * (float)lc[r];
    negs = waveSum(negs);
    unsigned c = waveSumU(lc[r]);
    if (lane == 0) { shn[r][wid] = negs; shc[r][wid] = c; }
  }
  __syncthreads();

  if (t == 0) {
#pragma unroll
    for (int r = 0; r < TR; ++r) {
      float bn = shn[r][0];
      unsigned bc = shc[r][0];
#pragma unroll
      for (int w = 1; w < NW; ++w) { bn += shn[r][w]; bc += shc[r][w]; }
      // positive term: diagonal only, scalar once per row
      float pd = __expf(fmaf(100.0f, dr[r], -C[r]));
      pd = fminf(fmaxf(pd, EPS), 1.0f - EPS);
      pos_out[row0 + r] = -__logf(pd);
      neg_out[row0 + r] = bn;
      cnt_out[row0 + r] = bc;
    }
  }
}

// single-block final reduction over 8192 per-row partials (96 KB)
__launch_bounds__(1024)
__global__ void reduce_final(const float* __restrict__ pos_in,
                             const float* __restrict__ neg_in,
                             const unsigned* __restrict__ cnt_in,
                             float* __restrict__ out) {
  __shared__ double shp[16], shn[16];
  __shared__ unsigned long long shc[16];

  const int t    = threadIdx.x;
  const int wid  = t >> 6;
  const int lane = t & 63;

  float ps = 0.0f, ns = 0.0f;
  unsigned cs = 0;
  const float4* pp = reinterpret_cast<const float4*>(pos_in);
  const float4* np = reinterpret_cast<const float4*>(neg_in);
  const uint4*  cp = reinterpret_cast<const uint4*>(cnt_in);
#pragma unroll
  for (int k = 0; k < 2; ++k) {   // 8192/4/1024 = 2
    float4 a = pp[k * 1024 + t];
    float4 b = np[k * 1024 + t];
    uint4  c = cp[k * 1024 + t];
    ps += a.x + a.y + a.z + a.w;
    ns += b.x + b.y + b.z + b.w;
    cs += c.x + c.y + c.z + c.w;
  }
  ps = waveSum(ps);
  ns = waveSum(ns);
  cs = waveSumU(cs);
  if (lane == 0) { shp[wid] = (double)ps; shn[wid] = (double)ns; shc[wid] = (unsigned long long)cs; }
  __syncthreads();
  if (t == 0) {
    double bp = 0.0, bn = 0.0;
    unsigned long long bc = 0;
#pragma unroll
    for (int w = 0; w < 16; ++w) { bp += shp[w]; bn += shn[w]; bc += shc[w]; }
    double pos_mean = bp / (double)N;
    double neg = (bc > 0ull) ? 0.5 * (bn / (double)bc) : 0.0;
    out[0] = (float)(pos_mean + neg);
  }
}

} // namespace

extern "C" void kernel_launch(void* const* d_in, const int* in_sizes, int n_in,
                              void* d_out, int out_size, void* d_ws, size_t ws_size,
                              hipStream_t stream) {
  const float* sim = (const float*)d_in[0];
  float* out = (float*)d_out;

  // workspace layout (all rewritten every call before being read):
  // [0,32K)    float pos[8192]
  // [32K,64K)  float neg[8192]
  // [64K,96K)  uint  cnt[8192]
  // [96K,128K) float diag[8192]
  float*    pos = (float*)d_ws;
  float*    neg = (float*)((char*)d_ws + 32 * 1024);
  unsigned* cnt = (unsigned*)((char*)d_ws + 64 * 1024);
  float*    dg  = (float*)((char*)d_ws + 96 * 1024);

  diag_extract<<<N / 256, 256, 0, stream>>>(sim, dg);
  row_loss<<<N / TR, NT, 0, stream>>>(sim, dg, pos, neg, cnt);
  reduce_final<<<1, 1024, 0, stream>>>(pos, neg, cnt, out);
}

// Round 8
// 61.174 us; speedup vs baseline: 1.5894x; 1.5894x over previous
//
#include <hip/hip_runtime.h>
#include <math.h>

namespace {

constexpr int N    = 8192;
constexpr int NSTR = 8;            // column stripes
constexpr int W    = N / NSTR;     // 1024 columns per stripe
constexpr int NT   = 256;          // threads per block (4 waves)
constexpr int NW   = NT / 64;
constexpr int RPB  = 32;           // rows per block
constexpr int RPW  = RPB / NW;     // 8 rows per wave
constexpr int F4L  = W / 64 / 4;   // 4 float4 per lane per row
constexpr float EPS = 1e-6f;
constexpr float NLOG_EPS = 13.815511f;   // -ln(1e-6)
constexpr float NEG_INF  = -3.4e38f;

__device__ __forceinline__ float waveSum(float v) {
#pragma unroll
  for (int off = 32; off; off >>= 1) v += __shfl_xor(v, off, 64);
  return v;
}
__device__ __forceinline__ unsigned waveSumU(unsigned v) {
#pragma unroll
  for (int off = 32; off; off >>= 1) v += (unsigned)__shfl_xor((int)v, off, 64);
  return v;
}

__global__ void diag_extract(const float* __restrict__ sim, float* __restrict__ dg) {
  int i = blockIdx.x * blockDim.x + threadIdx.x;
  if (i < N) dg[i] = sim[(size_t)i * N + i];
}

// Each block: one 1024-col stripe x 32 rows. One wave per row-stripe.
// Diag slice for the stripe lives in 16 VGPRs/lane, loaded once per block.
__launch_bounds__(NT)
__global__ void stripe_sweep(const float* __restrict__ sim,
                             const float* __restrict__ dg,
                             float* __restrict__ mS, float* __restrict__ zS,
                             float* __restrict__ s1S, float* __restrict__ s2S,
                             unsigned* __restrict__ cS) {
  const int blk  = blockIdx.x;
  const int s    = blk & (NSTR - 1);
  const int g    = blk >> 3;             // row group
  const int t    = threadIdx.x;
  const int wid  = t >> 6;
  const int lane = t & 63;
  const int col0 = s * W;

  // ---- stripe diag slice -> registers, once per block ----
  const float4* dp = reinterpret_cast<const float4*>(dg + col0);
  float4 dc[F4L];
#pragma unroll
  for (int i4 = 0; i4 < F4L; ++i4) dc[i4] = dp[i4 * 64 + lane];

#pragma unroll 1
  for (int i = 0; i < RPW; ++i) {
    const int row = g * RPB + wid * RPW + i;
    const float4* rp = reinterpret_cast<const float4*>(sim + (size_t)row * N + col0);
    const float dr = dg[row];            // same addr across wave: broadcast

    // ---- load this row-stripe: 16 elems/lane ----
    float4 xv[F4L];
#pragma unroll
    for (int i4 = 0; i4 < F4L; ++i4) xv[i4] = rp[i4 * 64 + lane];

    // ---- local top-2 overall, top-2 selected, count ----
    float t1 = NEG_INF, t2 = NEG_INF, s1 = NEG_INF, s2 = NEG_INF;
    unsigned c = 0;
#pragma unroll
    for (int i4 = 0; i4 < F4L; ++i4) {
#pragma unroll
      for (int cc = 0; cc < 4; ++cc) {
        const float xi = (cc == 0) ? xv[i4].x : (cc == 1) ? xv[i4].y : (cc == 2) ? xv[i4].z : xv[i4].w;
        const float dv = (cc == 0) ? dc[i4].x : (cc == 1) ? dc[i4].y : (cc == 2) ? dc[i4].z : dc[i4].w;
        const bool sel = xi > fminf(dr, dv);     // diagonal auto-excluded
        c += sel ? 1u : 0u;
        t2 = fmaxf(t2, fminf(xi, t1));
        t1 = fmaxf(t1, xi);
        const float xs = sel ? xi : NEG_INF;
        s2 = fmaxf(s2, fminf(xs, s1));
        s1 = fmaxf(s1, xs);
      }
    }

    // ---- butterfly merge across the wave (top-2 pairs + count) ----
#pragma unroll
    for (int off = 32; off; off >>= 1) {
      float ot1 = __shfl_xor(t1, off, 64), ot2 = __shfl_xor(t2, off, 64);
      t2 = fmaxf(fminf(t1, ot1), fmaxf(t2, ot2));
      t1 = fmaxf(t1, ot1);
      float os1 = __shfl_xor(s1, off, 64), os2 = __shfl_xor(s2, off, 64);
      s2 = fmaxf(fminf(s1, os1), fmaxf(s2, os2));
      s1 = fmaxf(s1, os1);
      c += (unsigned)__shfl_xor((int)c, off, 64);
    }

    // ---- stripe Z: exact over kept x with cutoff m-0.2 (rel err < 2e-5) ----
    const float m  = t1;
    const float zc = m - 0.2f;
    float zl = 0.0f;
#pragma unroll
    for (int i4 = 0; i4 < F4L; ++i4) {
#pragma unroll
      for (int cc = 0; cc < 4; ++cc) {
        const float xi = (cc == 0) ? xv[i4].x : (cc == 1) ? xv[i4].y : (cc == 2) ? xv[i4].z : xv[i4].w;
        if (__builtin_expect(xi > zc, 0)) zl += __expf(100.0f * (xi - m));
      }
    }
    zl = waveSum(zl);

    if (lane == 0) {
      const int o = s * N + row;
      mS[o]  = m;
      zS[o]  = zl;
      s1S[o] = s1;
      s2S[o] = s2;
      cS[o]  = c;
    }
  }
}

// One thread per row: merge 8 stripes -> per-row (pos, neg, cnt)
__launch_bounds__(NT)
__global__ void row_merge(const float* __restrict__ mS, const float* __restrict__ zS,
                          const float* __restrict__ s1S, const float* __restrict__ s2S,
                          const unsigned* __restrict__ cS,
                          const float* __restrict__ dg,
                          float* __restrict__ pos_out, float* __restrict__ neg_out,
                          unsigned* __restrict__ cnt_out) {
  const int row = blockIdx.x * blockDim.x + threadIdx.x;
  if (row >= N) return;

  // ---- row max over stripes ----
  float M = NEG_INF;
  float ms[NSTR];
#pragma unroll
  for (int s = 0; s < NSTR; ++s) { ms[s] = mS[s * N + row]; M = fmaxf(M, ms[s]); }

  // ---- Z: online-softmax merge of stripe partials ----
  float Z = 0.0f;
#pragma unroll
  for (int s = 0; s < NSTR; ++s) Z += zS[s * N + row] * __expf(100.0f * (ms[s] - M));

  // ---- top-2 selected over stripes ----
  float s1 = NEG_INF, s2 = NEG_INF;
  unsigned c = 0;
#pragma unroll
  for (int s = 0; s < NSTR; ++s) {
    const float a1 = s1S[s * N + row], a2 = s2S[s * N + row];
    s2 = fmaxf(fminf(s1, a1), fmaxf(s2, a2));
    s1 = fmaxf(s1, a1);
    c += cS[s * N + row];
  }

  // p = exp(100x - C), C = 100M + ln Z
  const float C    = fmaf(100.0f, M, __logf(Z));
  const float xthr = (C - NLOG_EPS) * 0.01f;   // below: clipped term == EPS

  // ---- positive term (diagonal) ----
  const float dr = dg[row];
  float pd = __expf(fmaf(100.0f, dr, -C));
  pd = fminf(fmaxf(pd, EPS), 1.0f - EPS);
  pos_out[row] = -__logf(pd);

  // ---- neg: rare exact terms + baseline EPS per selected ----
  float negs = 0.0f;
  if (s1 > xthr) {
    float p  = __expf(fmaf(100.0f, s1, -C));
    float pc = fminf(fmaxf(p, EPS), 1.0f - EPS);
    negs += -__logf(1.0f - pc) - EPS;
  }
  if (s2 > xthr) {
    float p  = __expf(fmaf(100.0f, s2, -C));
    float pc = fminf(fmaxf(p, EPS), 1.0f - EPS);
    negs += -__logf(1.0f - pc) - EPS;
  }
  negs += EPS * (float)c;
  neg_out[row] = negs;
  cnt_out[row] = c;
}

// single-block final reduction over 8192 per-row partials (96 KB)
__launch_bounds__(1024)
__global__ void reduce_final(const float* __restrict__ pos_in,
                             const float* __restrict__ neg_in,
                             const unsigned* __restrict__ cnt_in,
                             float* __restrict__ out) {
  __shared__ double shp[16], shn[16];
  __shared__ unsigned long long shc[16];

  const int t    = threadIdx.x;
  const int wid  = t >> 6;
  const int lane = t & 63;

  float ps = 0.0f, ns = 0.0f;
  unsigned cs = 0;
  const float4* pp = reinterpret_cast<const float4*>(pos_in);
  const float4* np = reinterpret_cast<const float4*>(neg_in);
  const uint4*  cp = reinterpret_cast<const uint4*>(cnt_in);
#pragma unroll
  for (int k = 0; k < 2; ++k) {   // 8192/4/1024 = 2
    float4 a = pp[k * 1024 + t];
    float4 b = np[k * 1024 + t];
    uint4  q = cp[k * 1024 + t];
    ps += a.x + a.y + a.z + a.w;
    ns += b.x + b.y + b.z + b.w;
    cs += q.x + q.y + q.z + q.w;
  }
  ps = waveSum(ps);
  ns = waveSum(ns);
  cs = waveSumU(cs);
  if (lane == 0) { shp[wid] = (double)ps; shn[wid] = (double)ns; shc[wid] = (unsigned long long)cs; }
  __syncthreads();
  if (t == 0) {
    double bp = 0.0, bn = 0.0;
    unsigned long long bc = 0;
#pragma unroll
    for (int w = 0; w < 16; ++w) { bp += shp[w]; bn += shn[w]; bc += shc[w]; }
    double pos_mean = bp / (double)N;
    double neg = (bc > 0ull) ? 0.5 * (bn / (double)bc) : 0.0;
    out[0] = (float)(pos_mean + neg);
  }
}

} // namespace

extern "C" void kernel_launch(void* const* d_in, const int* in_sizes, int n_in,
                              void* d_out, int out_size, void* d_ws, size_t ws_size,
                              hipStream_t stream) {
  const float* sim = (const float*)d_in[0];
  float* out = (float*)d_out;

  // workspace layout (~1.41 MB, all rewritten every call before being read):
  // [0,256K)        float m[8][8192]
  // [256K,512K)     float z[8][8192]
  // [512K,768K)     float s1[8][8192]
  // [768K,1M)       float s2[8][8192]
  // [1M,1.25M)      uint  c[8][8192]
  // [1.25M,+32K)    float pos[8192]
  // [+32K,+64K)     float neg[8192]
  // [+64K,+96K)     uint  cnt[8192]
  // [+96K,+128K)    float diag[8192]
  char* w = (char*)d_ws;
  float*    mS  = (float*)(w);
  float*    zS  = (float*)(w + 256 * 1024);
  float*    s1S = (float*)(w + 512 * 1024);
  float*    s2S = (float*)(w + 768 * 1024);
  unsigned* cS  = (unsigned*)(w + 1024 * 1024);
  float*    pos = (float*)(w + 1280 * 1024);
  float*    neg = (float*)(w + 1312 * 1024);
  unsigned* cnt = (unsigned*)(w + 1344 * 1024);
  float*    dg  = (float*)(w + 1376 * 1024);

  diag_extract<<<N / 256, 256, 0, stream>>>(sim, dg);
  stripe_sweep<<<NSTR * (N / RPB), NT, 0, stream>>>(sim, dg, mS, zS, s1S, s2S, cS);
  row_merge<<<N / NT, NT, 0, stream>>>(mS, zS, s1S, s2S, cS, dg, pos, neg, cnt);
  reduce_final<<<1, 1024, 0, stream>>>(pos, neg, cnt, out);
}

// Round 9
// 59.987 us; speedup vs baseline: 1.6208x; 1.0198x over previous
//
#include <hip/hip_runtime.h>
#include <math.h>

namespace {

constexpr int N   = 8192;
constexpr int NT  = 512;          // threads per block (8 waves)
constexpr int PF4 = N / 4 / NT;   // 4 float4 per thread
constexpr int NW  = NT / 64;
constexpr float EPS = 1e-6f;
constexpr float NLOG_EPS = 13.815511f;   // -ln(1e-6)
constexpr float NEG_INF  = -3.4e38f;

__device__ __forceinline__ float waveMax(float v) {
#pragma unroll
  for (int off = 32; off; off >>= 1) v = fmaxf(v, __shfl_xor(v, off, 64));
  return v;
}
__device__ __forceinline__ float waveSum(float v) {
#pragma unroll
  for (int off = 32; off; off >>= 1) v += __shfl_xor(v, off, 64);
  return v;
}
__device__ __forceinline__ unsigned waveSumU(unsigned v) {
#pragma unroll
  for (int off = 32; off; off >>= 1) v += (unsigned)__shfl_xor((int)v, off, 64);
  return v;
}

__global__ void diag_extract(const float* __restrict__ sim, float* __restrict__ dg) {
  int i = blockIdx.x * blockDim.x + threadIdx.x;
  if (i < N) dg[i] = sim[(size_t)i * N + i];
}

__launch_bounds__(NT)
__global__ void row_loss(const float* __restrict__ sim,
                         const float* __restrict__ dg,
                         float* __restrict__ pos_out,
                         float* __restrict__ neg_out,
                         unsigned* __restrict__ cnt_out) {
  __shared__ float shm[NW];    // per-wave max
  __shared__ float shz[NW];    // per-wave Z partial
  __shared__ float shn[NW];    // per-wave neg sums
  __shared__ unsigned shc[NW]; // per-wave counts

  const int row  = blockIdx.x;
  const int t    = threadIdx.x;
  const int wid  = t >> 6;
  const int lane = t & 63;

  const float4* rp = reinterpret_cast<const float4*>(sim + (size_t)row * N);
  const float4* dp = reinterpret_cast<const float4*>(dg);
  const float dr = dg[row];

  // ---- issue ALL loads first: 4 matrix float4 + 4 diag float4 per thread ----
  float4 xv[PF4], dv[PF4];
#pragma unroll
  for (int k = 0; k < PF4; ++k) xv[k] = rp[k * NT + t];
#pragma unroll
  for (int k = 0; k < PF4; ++k) dv[k] = dp[k * NT + t];

  // ---- single pass: top-2 overall, top-2 selected, selection count ----
  float t1 = NEG_INF, t2 = NEG_INF;
  float s1 = NEG_INF, s2 = NEG_INF;
  unsigned lc = 0;
#pragma unroll
  for (int k = 0; k < PF4; ++k) {
#pragma unroll
    for (int c = 0; c < 4; ++c) {
      const float xi = (c == 0) ? xv[k].x : (c == 1) ? xv[k].y : (c == 2) ? xv[k].z : xv[k].w;
      const float dc = (c == 0) ? dv[k].x : (c == 1) ? dv[k].y : (c == 2) ? dv[k].z : dv[k].w;
      const bool sel = xi > fminf(dr, dc);   // diagonal auto-excluded (xi==dr==dc)
      lc += sel ? 1u : 0u;
      t2 = fmaxf(t2, fminf(xi, t1));
      t1 = fmaxf(t1, xi);
      const float xs = sel ? xi : NEG_INF;
      s2 = fmaxf(s2, fminf(xs, s1));
      s1 = fmaxf(s1, xs);
    }
  }

  // ---- block max M ----
  float lm = waveMax(t1);
  if (lane == 0) shm[wid] = lm;
  __syncthreads();
  float M = shm[0];
#pragma unroll
  for (int w = 1; w < NW; ++w) M = fmaxf(M, shm[w]);

  // ---- Z from each thread's kept top-2 (cutoff M-0.2: rel err < 2e-5) ----
  const float zc = M - 0.2f;
  float zp = 0.0f;
  if (t1 > zc) zp += __expf(100.0f * (t1 - M));
  if (t2 > zc) zp += __expf(100.0f * (t2 - M));
  zp = waveSum(zp);
  if (lane == 0) shz[wid] = zp;
  __syncthreads();
  float Z = shz[0];
#pragma unroll
  for (int w = 1; w < NW; ++w) Z += shz[w];

  // p_j = exp(100*x_j - C),  C = 100*M + ln Z
  const float C    = fmaf(100.0f, M, __logf(Z));
  const float xthr = (C - NLOG_EPS) * 0.01f;  // below: p < EPS -> term == EPS

  // ---- exact neg path from kept selected values (~1 per row above xthr) ----
  float negs = 0.0f;
  if (s1 > xthr) {
    float p  = __expf(fmaf(100.0f, s1, -C));
    float pc = fminf(fmaxf(p, EPS), 1.0f - EPS);
    negs += -__logf(1.0f - pc) - EPS;
  }
  if (s2 > xthr) {
    float p  = __expf(fmaf(100.0f, s2, -C));
    float pc = fminf(fmaxf(p, EPS), 1.0f - EPS);
    negs += -__logf(1.0f - pc) - EPS;
  }
  negs += EPS * (float)lc;   // baseline EPS for every selected element

  negs = waveSum(negs);
  lc   = waveSumU(lc);
  if (lane == 0) { shn[wid] = negs; shc[wid] = lc; }
  __syncthreads();
  if (t == 0) {
    float bn = 0.0f;
    unsigned bc = 0;
#pragma unroll
    for (int w = 0; w < NW; ++w) { bn += shn[w]; bc += shc[w]; }
    // positive term: diagonal only, scalar once per row
    float pd = __expf(fmaf(100.0f, dr, -C));
    pd = fminf(fmaxf(pd, EPS), 1.0f - EPS);
    pos_out[row] = -__logf(pd);
    neg_out[row] = bn;
    cnt_out[row] = bc;
  }
}

// single-block final reduction over 8192 per-row partials (96 KB)
__launch_bounds__(1024)
__global__ void reduce_final(const float* __restrict__ pos_in,
                             const float* __restrict__ neg_in,
                             const unsigned* __restrict__ cnt_in,
                             float* __restrict__ out) {
  __shared__ double shp[16], shn[16];
  __shared__ unsigned long long shc[16];

  const int t    = threadIdx.x;
  const int wid  = t >> 6;
  const int lane = t & 63;

  float ps = 0.0f, ns = 0.0f;
  unsigned cs = 0;
  const float4* pp = reinterpret_cast<const float4*>(pos_in);
  const float4* np = reinterpret_cast<const float4*>(neg_in);
  const uint4*  cp = reinterpret_cast<const uint4*>(cnt_in);
#pragma unroll
  for (int k = 0; k < 2; ++k) {   // 8192/4/1024 = 2
    float4 a = pp[k * 1024 + t];
    float4 b = np[k * 1024 + t];
    uint4  c = cp[k * 1024 + t];
    ps += a.x + a.y + a.z + a.w;
    ns += b.x + b.y + b.z + b.w;
    cs += c.x + c.y + c.z + c.w;
  }
  ps = waveSum(ps);
  ns = waveSum(ns);
  cs = waveSumU(cs);
  if (lane == 0) { shp[wid] = (double)ps; shn[wid] = (double)ns; shc[wid] = (unsigned long long)cs; }
  __syncthreads();
  if (t == 0) {
    double bp = 0.0, bn = 0.0;
    unsigned long long bc = 0;
#pragma unroll
    for (int w = 0; w < 16; ++w) { bp += shp[w]; bn += shn[w]; bc += shc[w]; }
    double pos_mean = bp / (double)N;
    double neg = (bc > 0ull) ? 0.5 * (bn / (double)bc) : 0.0;
    out[0] = (float)(pos_mean + neg);
  }
}

} // namespace

extern "C" void kernel_launch(void* const* d_in, const int* in_sizes, int n_in,
                              void* d_out, int out_size, void* d_ws, size_t ws_size,
                              hipStream_t stream) {
  const float* sim = (const float*)d_in[0];
  float* out = (float*)d_out;

  // workspace layout (all rewritten every call before being read):
  // [0,32K)    float pos[8192]
  // [32K,64K)  float neg[8192]
  // [64K,96K)  uint  cnt[8192]
  // [96K,128K) float diag[8192]
  float*    pos = (float*)d_ws;
  float*    neg = (float*)((char*)d_ws + 32 * 1024);
  unsigned* cnt = (unsigned*)((char*)d_ws + 64 * 1024);
  float*    dg  = (float*)((char*)d_ws + 96 * 1024);

  diag_extract<<<N / 256, 256, 0, stream>>>(sim, dg);
  row_loss<<<N, NT, 0, stream>>>(sim, dg, pos, neg, cnt);
  reduce_final<<<1, 1024, 0, stream>>>(pos, neg, cnt, out);
}

// Round 10
// 56.788 us; speedup vs baseline: 1.7122x; 1.0563x over previous
//
#include <hip/hip_runtime.h>
#include <math.h>

namespace {

constexpr int N  = 8192;
constexpr int NT = 256;          // threads per block
constexpr int F4 = N / 4 / NT;   // 8 float4 per thread -> 32 floats
constexpr float EPS = 1e-6f;
constexpr float NLOG_EPS = 13.815511f;   // -ln(1e-6)

__device__ __forceinline__ float waveSum(float v) {
#pragma unroll
  for (int off = 32; off; off >>= 1) v += __shfl_xor(v, off, 64);
  return v;
}
__device__ __forceinline__ unsigned waveSumU(unsigned v) {
#pragma unroll
  for (int off = 32; off; off >>= 1) v += (unsigned)__shfl_xor((int)v, off, 64);
  return v;
}

__global__ void diag_extract(const float* __restrict__ sim, float* __restrict__ dg) {
  int i = blockIdx.x * blockDim.x + threadIdx.x;
  if (i < N) dg[i] = sim[(size_t)i * N + i];
}

__launch_bounds__(NT)
__global__ void row_loss(const float* __restrict__ sim,
                         const float* __restrict__ dg,
                         float* __restrict__ pos_out,
                         float* __restrict__ neg_out,
                         unsigned* __restrict__ cnt_out) {
  __shared__ float shm[4];   // per-wave running max
  __shared__ float shs[4];   // per-wave running sum (scaled to shm)
  __shared__ float shn[4];   // per-wave neg sums
  __shared__ float shp[4];   // per-wave pos terms
  __shared__ unsigned shc[4];// per-wave counts

  const int row  = blockIdx.x;
  const int t    = threadIdx.x;
  const int wid  = t >> 6;
  const int lane = t & 63;

  const float4* rp = reinterpret_cast<const float4*>(sim + (size_t)row * N);
  const float4* dp = reinterpret_cast<const float4*>(dg);

  // ---- load whole row into registers (coalesced float4) ----
  float x[F4 * 4];
#pragma unroll
  for (int k = 0; k < F4; ++k) {
    float4 v = rp[k * NT + t];
    x[4 * k + 0] = v.x;
    x[4 * k + 1] = v.y;
    x[4 * k + 2] = v.z;
    x[4 * k + 3] = v.w;
  }

  // ---- per-thread local max, then local scaled sum (no barrier) ----
  float lm = x[0];
#pragma unroll
  for (int i = 1; i < F4 * 4; ++i) lm = fmaxf(lm, x[i]);
  float ls = 0.0f;
#pragma unroll
  for (int i = 0; i < F4 * 4; ++i) ls += __expf(100.0f * (x[i] - lm));

  // ---- wave-level (m,s) combine via shuffles ----
#pragma unroll
  for (int off = 32; off; off >>= 1) {
    float om = __shfl_xor(lm, off, 64);
    float os = __shfl_xor(ls, off, 64);
    float nm = fmaxf(lm, om);
    ls = ls * __expf(100.0f * (lm - nm)) + os * __expf(100.0f * (om - nm));
    lm = nm;
  }
  if (lane == 0) { shm[wid] = lm; shs[wid] = ls; }
  __syncthreads();   // the ONLY block barrier

  // ---- combine 4 wave pairs (every thread, redundantly) ----
  float M = fmaxf(fmaxf(shm[0], shm[1]), fmaxf(shm[2], shm[3]));
  float Z = shs[0] * __expf(100.0f * (shm[0] - M))
          + shs[1] * __expf(100.0f * (shm[1] - M))
          + shs[2] * __expf(100.0f * (shm[2] - M))
          + shs[3] * __expf(100.0f * (shm[3] - M));
  // p_j = exp(100*x_j - C),  C = 100*M + ln Z
  const float C  = fmaf(100.0f, M, __logf(Z));
  const float dr = dg[row];
  // below xthr, p < EPS -> clipped -> -log(1-p) == EPS exactly (to 5e-13)
  const float xthr = (C - NLOG_EPS) * 0.01f;

  // ---- positive term: diagonal only, once per block ----
  float posv = 0.0f;
  if (t == 0) {
    float pd = __expf(fmaf(100.0f, dr, -C));
    pd = fminf(fmaxf(pd, EPS), 1.0f - EPS);
    posv = -__logf(pd);
  }

  // ---- per-element: selection count + rare exact path ----
  float negs = 0.0f;
  unsigned lc = 0;
#pragma unroll
  for (int k = 0; k < F4; ++k) {
    float4 dv = dp[k * NT + t];
#pragma unroll
    for (int c = 0; c < 4; ++c) {
      const float xi = x[4 * k + c];
      const float dc = (c == 0) ? dv.x : (c == 1) ? dv.y : (c == 2) ? dv.z : dv.w;
      const bool sel = xi > fminf(dr, dc);   // diagonal auto-excluded (x==dr==dc)
      lc += sel ? 1u : 0u;
      if (__builtin_expect(xi > xthr, 0)) {  // ~1-2 elements per ROW
        if (sel) {
          float p  = __expf(fmaf(100.0f, xi, -C));
          float pc = fminf(fmaxf(p, EPS), 1.0f - EPS);
          negs += -__logf(1.0f - pc) - EPS;  // replaces the default EPS term
        }
      }
    }
  }
  negs += EPS * (float)lc;                   // every selected element baseline EPS

  negs = waveSum(negs);
  posv = waveSum(posv);
  lc   = waveSumU(lc);
  if (lane == 0) { shn[wid] = negs; shp[wid] = posv; shc[wid] = lc; }
  __syncthreads();
  if (t == 0) {
    pos_out[row] = shp[0] + shp[1] + shp[2] + shp[3];
    neg_out[row] = shn[0] + shn[1] + shn[2] + shn[3];
    cnt_out[row] = shc[0] + shc[1] + shc[2] + shc[3];
  }
}

// single-block final reduction over 8192 per-row partials (96 KB)
__launch_bounds__(1024)
__global__ void reduce_final(const float* __restrict__ pos_in,
                             const float* __restrict__ neg_in,
                             const unsigned* __restrict__ cnt_in,
                             float* __restrict__ out) {
  __shared__ double shp[16], shn[16];
  __shared__ unsigned long long shc[16];

  const int t    = threadIdx.x;
  const int wid  = t >> 6;
  const int lane = t & 63;

  float ps = 0.0f, ns = 0.0f;
  unsigned cs = 0;
  const float4* pp = reinterpret_cast<const float4*>(pos_in);
  const float4* np = reinterpret_cast<const float4*>(neg_in);
  const uint4*  cp = reinterpret_cast<const uint4*>(cnt_in);
#pragma unroll
  for (int k = 0; k < 2; ++k) {   // 8192/4/1024 = 2
    float4 a = pp[k * 1024 + t];
    float4 b = np[k * 1024 + t];
    uint4  c = cp[k * 1024 + t];
    ps += a.x + a.y + a.z + a.w;
    ns += b.x + b.y + b.z + b.w;
    cs += c.x + c.y + c.z + c.w;
  }
  ps = waveSum(ps);
  ns = waveSum(ns);
  cs = waveSumU(cs);
  if (lane == 0) { shp[wid] = (double)ps; shn[wid] = (double)ns; shc[wid] = (unsigned long long)cs; }
  __syncthreads();
  if (t == 0) {
    double bp = 0.0, bn = 0.0;
    unsigned long long bc = 0;
#pragma unroll
    for (int w = 0; w < 16; ++w) { bp += shp[w]; bn += shn[w]; bc += shc[w]; }
    double pos_mean = bp / (double)N;
    double neg = (bc > 0ull) ? 0.5 * (bn / (double)bc) : 0.0;
    out[0] = (float)(pos_mean + neg);
  }
}

} // namespace

extern "C" void kernel_launch(void* const* d_in, const int* in_sizes, int n_in,
                              void* d_out, int out_size, void* d_ws, size_t ws_size,
                              hipStream_t stream) {
  const float* sim = (const float*)d_in[0];
  float* out = (float*)d_out;

  // workspace layout (all rewritten every call before being read):
  // [0,32K)    float pos[8192]
  // [32K,64K)  float neg[8192]
  // [64K,96K)  uint  cnt[8192]
  // [96K,128K) float diag[8192]
  float*    pos = (float*)d_ws;
  float*    neg = (float*)((char*)d_ws + 32 * 1024);
  unsigned* cnt = (unsigned*)((char*)d_ws + 64 * 1024);
  float*    dg  = (float*)((char*)d_ws + 96 * 1024);

  diag_extract<<<N / 256, 256, 0, stream>>>(sim, dg);
  row_loss<<<N, NT, 0, stream>>>(sim, dg, pos, neg, cnt);
  reduce_final<<<1, 1024, 0, stream>>>(pos, neg, cnt, out);
}